// Round 2
// baseline (140.764 us; speedup 1.0000x reference)
//
#include <hip/hip_runtime.h>
#include <stdint.h>

// Problem constants (match reference)
#define Bn   256
#define Dn   2048
#define Sn   8
#define ON   1000

// Tiling: single kernel, full-K per block.
#define ROWS 64             // max samples per subject (binomial mean 32; 6+ sigma)
#define OT   32             // output columns per block -> 32 oc blocks x 8 s = 256 blocks (1/CU)
#define KC   256            // k per tile
#define NKT  (Dn / KC)      // 8 k-tiles, streamed with depth-2 register ring
#define LDK  (KC + 8)       // LDS row stride (ushorts) = 264 (16B aligned, bank-staggered)

typedef short v8s __attribute__((ext_vector_type(8)));
typedef float v4f __attribute__((ext_vector_type(4)));

// fp32 -> bf16 round-to-nearest-even (proven numerics from prior rounds)
static __device__ __forceinline__ short f2bf(float f) {
    union { float f; uint32_t u; } v; v.f = f;
    uint32_t u = v.u;
    u += 0x7FFFu + ((u >> 16) & 1u);
    return (short)(u >> 16);
}

// One kernel does everything:
//  - bucket rows of subject s (ballot, deterministic)
//  - stream W[s, :, o-tile] through a depth-2 register ring -> LDS (bf16)
//  - A-fragments straight from x (L2-resident) with inline cvt
//  - raw s_barrier + lgkmcnt(0) per tile: next tile's global loads stay in
//    flight across the barrier (no vmcnt drain -> HBM never idles)
//  - epilogue fuses bias and stores out directly (no part buffer, no reduce)
__global__ __launch_bounds__(256) void main_kernel(const float* __restrict__ x,
                                                   const int* __restrict__ sid,
                                                   const float* __restrict__ W,
                                                   const float* __restrict__ bias,
                                                   float* __restrict__ out) {
    __shared__ unsigned short Bsh[2][OT * LDK];   // double-buffered B[o][k] bf16 tile
    __shared__ unsigned long long bmask[4];
    __shared__ int rows_l[ROWS];

    const int oc = blockIdx.x;   // 0..31
    const int s  = blockIdx.y;   // 0..7
    const int o0 = oc * OT;
    const int t  = threadIdx.x;
    const int lane = t & 63;
    const int wave = t >> 6;

    // ---- bucket samples of subject s via ballot (prefix-dense rows_l) ----
    const bool match = (sid[t] == s);
    const unsigned long long m = __ballot(match);
    if (lane == 0) bmask[wave] = m;
    if (t < ROWS) rows_l[t] = -1;
    __syncthreads();
    if (match) {
        int pos = __popcll(m & ((1ull << lane) - 1ull));
        for (int w = 0; w < wave; ++w) pos += __popcll(bmask[w]);
        if (pos < ROWS) rows_l[pos] = t;
    }
    __syncthreads();

    // ---- B staging geometry: thread covers o = o0+(t&31) (clamped),
    //      k-rows kr*32..kr*32+31 per tile (kr = t>>5). Scalar loads are
    //      o-coalesced (32x4B = 128B segments per half-wave). ----
    int og = o0 + (t & 31); if (og > ON - 1) og = ON - 1;   // clamp; masked at store
    const int kr = t >> 5;
    const float* wp = W + (size_t)s * Dn * ON + (size_t)(kr * 32) * ON + og;
    const int boff = (t & 31) * LDK + kr * 32;

    // ---- A geometry: wave w owns rows w*16..w*16+15; frag k = quad*8..+8 ----
    const int lo16 = lane & 15;
    const int quad = lane >> 4;
    const int ar   = wave * 16 + lo16;
    const int xrow = rows_l[ar];
    const float* xp = (xrow >= 0 ? x + (size_t)xrow * Dn : x) + quad * 8;
    // prefix-dense fill => if first slot of this wave's range is empty, all are
    const bool wactive = (rows_l[wave * 16] >= 0);

    // ---- prologue: issue tiles 0 and 1, convert tile 0 into Bsh[0] ----
    float fbr0[32], fbr1[32];
#pragma unroll
    for (int j = 0; j < 32; ++j) fbr0[j] = wp[(size_t)j * ON];
#pragma unroll
    for (int j = 0; j < 32; ++j) fbr1[j] = wp[((size_t)KC + j) * ON];

#pragma unroll
    for (int g = 0; g < 4; ++g) {
        v8s bv;
#pragma unroll
        for (int j = 0; j < 8; ++j) bv[j] = f2bf(fbr0[g * 8 + j]);
        *(v8s*)&Bsh[0][boff + g * 8] = bv;
    }
    asm volatile("s_waitcnt lgkmcnt(0)" ::: "memory");
    __builtin_amdgcn_s_barrier();          // tile1 loads stay in flight (no vmcnt drain)
    asm volatile("" ::: "memory");

    v4f acc[2];
    acc[0] = (v4f){0.f, 0.f, 0.f, 0.f};
    acc[1] = (v4f){0.f, 0.f, 0.f, 0.f};

#define COMPUTE_TILE(KT, BUF)                                                        \
    if (wactive) {                                                                   \
        _Pragma("unroll")                                                            \
        for (int it = 0; it < 8; ++it) {                                             \
            const float4 f0 = *(const float4*)(xp + (size_t)(KT) * KC + it * 32);    \
            const float4 f1 = *(const float4*)(xp + (size_t)(KT) * KC + it * 32 + 4);\
            v8s af;                                                                  \
            af[0] = f2bf(f0.x); af[1] = f2bf(f0.y);                                  \
            af[2] = f2bf(f0.z); af[3] = f2bf(f0.w);                                  \
            af[4] = f2bf(f1.x); af[5] = f2bf(f1.y);                                  \
            af[6] = f2bf(f1.z); af[7] = f2bf(f1.w);                                  \
            _Pragma("unroll")                                                        \
            for (int nt = 0; nt < 2; ++nt) {                                         \
                const v8s bf = *(const v8s*)&Bsh[BUF][(nt * 16 + lo16) * LDK +       \
                                                      it * 32 + quad * 8];           \
                acc[nt] = __builtin_amdgcn_mfma_f32_16x16x32_bf16(af, bf, acc[nt],   \
                                                                  0, 0, 0);          \
            }                                                                        \
        }                                                                            \
    }

#define CVT_TILE(FBR, BUF)                                                           \
    {                                                                                \
        _Pragma("unroll")                                                            \
        for (int g = 0; g < 4; ++g) {                                                \
            v8s bv;                                                                  \
            _Pragma("unroll")                                                        \
            for (int j = 0; j < 8; ++j) bv[j] = f2bf(FBR[g * 8 + j]);                \
            *(v8s*)&Bsh[BUF][boff + g * 8] = bv;                                     \
        }                                                                            \
        asm volatile("s_waitcnt lgkmcnt(0)" ::: "memory");                           \
        __builtin_amdgcn_s_barrier();                                                \
        asm volatile("" ::: "memory");                                               \
    }

#define ISSUE_TILE(FBR, KT)                                                          \
    {                                                                                \
        _Pragma("unroll")                                                            \
        for (int j = 0; j < 32; ++j) FBR[j] = wp[((size_t)(KT) * KC + j) * ON];      \
    }

    // ---- main loop: two tiles per iteration, static register-ring indexing ----
#pragma unroll 1
    for (int kt = 0; kt < NKT; kt += 2) {
        // body A: compute tile kt from Bsh[0]; prefetch kt+2 -> fbr0
        if (kt + 2 < NKT) ISSUE_TILE(fbr0, kt + 2)
        COMPUTE_TILE(kt, 0)
        CVT_TILE(fbr1, 1)                     // tile kt+1 -> Bsh[1], barrier

        // body B: compute tile kt+1 from Bsh[1]; prefetch kt+3 -> fbr1
        if (kt + 3 < NKT) ISSUE_TILE(fbr1, kt + 3)
        COMPUTE_TILE(kt + 1, 1)
        if (kt + 2 < NKT) CVT_TILE(fbr0, 0)   // tile kt+2 -> Bsh[0], barrier
    }

#undef COMPUTE_TILE
#undef CVT_TILE
#undef ISSUE_TILE

    // ---- epilogue: C/D layout col=lane&15, row=quad*4+reg; fuse bias, store out ----
    if (wactive) {
        const int er0 = wave * 16 + quad * 4;
#pragma unroll
        for (int nt = 0; nt < 2; ++nt) {
            const int o = o0 + nt * 16 + lo16;
            if (o < ON) {
                const float bv = bias[(size_t)s * ON + o];
#pragma unroll
                for (int r = 0; r < 4; ++r) {
                    const int bi = rows_l[er0 + r];
                    if (bi >= 0) out[(size_t)bi * ON + o] = acc[nt][r] + bv;
                }
            }
        }
    }
}

extern "C" void kernel_launch(void* const* d_in, const int* in_sizes, int n_in,
                              void* d_out, int out_size, void* d_ws, size_t ws_size,
                              hipStream_t stream) {
    const float* x    = (const float*)d_in[0];
    const int*   sid  = (const int*)d_in[1];
    const float* W    = (const float*)d_in[2];
    const float* bias = (const float*)d_in[3];
    float*       out  = (float*)d_out;
    (void)d_ws; (void)ws_size;

    main_kernel<<<dim3(32, Sn), dim3(256), 0, stream>>>(x, sid, W, bias, out);
}

// Round 3
// 113.536 us; speedup vs baseline: 1.2398x; 1.2398x over previous
//
#include <hip/hip_runtime.h>
#include <stdint.h>

// Problem constants (match reference)
#define Bn   256
#define Dn   2048
#define Sn   8
#define ON   1000

// Tiling
#define ROWS 64             // max samples per subject (binomial mean 32; 6+ sigma)
#define OT   64             // output columns per block
#define NDC  4              // K-split factor (was 8): halves part-buffer traffic
#define KB   (Dn / NDC)     // 512 k per block
#define KC   256            // k per staged tile
#define NTL  (KB / KC)      // 2 tiles per block
#define NCH  (KC / 32)      // 8 staging chunks of 32 k per tile
#define LDK  (KC + 8)       // LDS row stride (ushorts) = 264 (16B aligned, bank-staggered)

typedef short v8s __attribute__((ext_vector_type(8)));
typedef float v4f __attribute__((ext_vector_type(4)));

// fp32 -> bf16 round-to-nearest-even
static __device__ __forceinline__ short f2bf(float f) {
    union { float f; uint32_t u; } v; v.f = f;
    uint32_t u = v.u;
    u += 0x7FFFu + ((u >> 16) & 1u);
    return (short)(u >> 16);
}

// Per-(o-chunk, k-quarter, subject) GEMM partial. 512 blocks = 2/CU: TLP
// desynchronizes stage/compute phases across co-resident blocks so HBM stays
// busy. Staging uses the PROVEN fine-grained ring: fb[2][8] = 16 VGPRs
// (round 2's fbr[64] collapsed at VGPR_Count=68 -> serial latency, 1.1 TB/s).
// A-fragments come straight from x (L2-resident, 2 MB) with inline cvt.
__global__ __launch_bounds__(256) void main_kernel(const float* __restrict__ x,
                                                   const int* __restrict__ sid,
                                                   const float* __restrict__ W,
                                                   float* __restrict__ part) {
    __shared__ unsigned short Bsh[OT * LDK];     // B[o][k] bf16, single buffer
    __shared__ unsigned long long bmask[4];
    __shared__ int rows_l[ROWS];

    const int oc = blockIdx.x;   // 0..15
    const int kc = blockIdx.y;   // 0..3
    const int s  = blockIdx.z;   // 0..7
    const int o0 = oc * OT;
    const int d0 = kc * KB;
    const int t  = threadIdx.x;
    const int lane = t & 63;
    const int wave = t >> 6;

    // ---- bucket samples of subject s via ballot (prefix-dense rows_l) ----
    const bool match = (sid[t] == s);
    const unsigned long long m = __ballot(match);
    if (lane == 0) bmask[wave] = m;
    if (t < ROWS) rows_l[t] = -1;
    __syncthreads();
    if (match) {
        int pos = __popcll(m & ((1ull << lane) - 1ull));
        for (int w = 0; w < wave; ++w) pos += __popcll(bmask[w]);
        if (pos < ROWS) rows_l[pos] = t;
    }
    __syncthreads();

    // ---- B staging geometry (round-0 proven): thread covers o = o0+lane
    //      (256B o-coalesced per wave), k-rows wave*8 + j per 32-k chunk ----
    int og = o0 + lane; if (og > ON - 1) og = ON - 1;   // clamp; masked at store
    const float* wp = W + (size_t)s * Dn * ON + (size_t)(d0 + wave * 8) * ON + og;
    const int boff = lane * LDK + wave * 8;

    // ---- A geometry: wave owns rows wave*16..+15; frag k = quad*8..+8 ----
    const int lo16 = lane & 15;
    const int quad = lane >> 4;
    const int ar   = wave * 16 + lo16;
    const int xrow = rows_l[ar];
    const float* xp = (xrow >= 0 ? x + (size_t)xrow * Dn : x) + d0 + quad * 8;
    const bool wactive = (rows_l[wave * 16] >= 0);   // prefix-dense

    v4f acc[4];
#pragma unroll
    for (int i = 0; i < 4; i++) acc[i] = (v4f){0.f, 0.f, 0.f, 0.f};

    // ---- prologue: issue global chunks 0,1 of the 16-chunk stream ----
    float fb[2][8];
#pragma unroll
    for (int c = 0; c < 2; ++c)
#pragma unroll
        for (int j = 0; j < 8; ++j) fb[c][j] = wp[(size_t)(c * 32 + j) * ON];

#pragma unroll
    for (int kt = 0; kt < NTL; ++kt) {
        // ---- stage tile kt: depth-2 ring over 8 chunks; chunk g (global index
        //      kt*8+c) lives in slot g&1 == c&1; loads for the NEXT tile's first
        //      two chunks are issued here and stay in flight through compute ----
#pragma unroll
        for (int c = 0; c < NCH; ++c) {
            const int sl = c & 1;
            v8s bv;
#pragma unroll
            for (int j = 0; j < 8; ++j) bv[j] = f2bf(fb[sl][j]);
            *(v8s*)&Bsh[boff + c * 32] = bv;
            const int gi = kt * NCH + c + 2;            // next chunk to issue
            if (gi < NTL * NCH) {
#pragma unroll
                for (int j = 0; j < 8; ++j) fb[sl][j] = wp[((size_t)gi * 32 + j) * ON];
            }
        }
        // stage->compute: drain ds_writes only (lgkm); vmcnt loads stay in flight
        asm volatile("s_waitcnt lgkmcnt(0)" ::: "memory");
        __builtin_amdgcn_s_barrier();
        asm volatile("" ::: "memory");

        // ---- compute tile kt ----
        if (wactive) {
#pragma unroll
            for (int it = 0; it < 8; ++it) {
                const float4 f0 = *(const float4*)(xp + kt * KC + it * 32);
                const float4 f1 = *(const float4*)(xp + kt * KC + it * 32 + 4);
                v8s af;
                af[0] = f2bf(f0.x); af[1] = f2bf(f0.y);
                af[2] = f2bf(f0.z); af[3] = f2bf(f0.w);
                af[4] = f2bf(f1.x); af[5] = f2bf(f1.y);
                af[6] = f2bf(f1.z); af[7] = f2bf(f1.w);
#pragma unroll
                for (int nt = 0; nt < 4; ++nt) {
                    const v8s bf = *(const v8s*)&Bsh[(nt * 16 + lo16) * LDK +
                                                     it * 32 + quad * 8];
                    acc[nt] = __builtin_amdgcn_mfma_f32_16x16x32_bf16(af, bf, acc[nt],
                                                                      0, 0, 0);
                }
            }
        }
        // compute->restage: protect Bsh overwrite; again no vmcnt drain
        if (kt + 1 < NTL) {
            asm volatile("s_waitcnt lgkmcnt(0)" ::: "memory");
            __builtin_amdgcn_s_barrier();
            asm volatile("" ::: "memory");
        }
    }

    // ---- epilogue: C/D layout col=lane&15, row=quad*4+reg ----
    if (wactive) {
        float* pp = part + (size_t)kc * Bn * ON;
        const int er0 = wave * 16 + quad * 4;
#pragma unroll
        for (int nt = 0; nt < 4; ++nt) {
            const int o = o0 + nt * 16 + lo16;
            if (o < ON) {
#pragma unroll
                for (int r = 0; r < 4; ++r) {
                    const int bi = rows_l[er0 + r];
                    if (bi >= 0) pp[(size_t)bi * ON + o] = acc[nt][r];
                }
            }
        }
    }
}

// Reduce: out[b][o] = bias[sid[b]][o] + sum_kc part[kc][b][o]  (float4 lanes)
__global__ __launch_bounds__(256) void reduce_kernel(const int* __restrict__ sid,
                                                     const float* __restrict__ bias,
                                                     const float* __restrict__ part,
                                                     float* __restrict__ out) {
    const int b = blockIdx.x;
    const int s = sid[b];
    const int o = threadIdx.x * 4;
    if (o < ON) {          // ON=1000 -> 250 active float4 lanes
        float4 v = *(const float4*)(bias + (size_t)s * ON + o);
#pragma unroll
        for (int d = 0; d < NDC; d++) {
            const float4 p = *(const float4*)(part + ((size_t)d * Bn + b) * ON + o);
            v.x += p.x; v.y += p.y; v.z += p.z; v.w += p.w;
        }
        *(float4*)(out + (size_t)b * ON + o) = v;
    }
}

extern "C" void kernel_launch(void* const* d_in, const int* in_sizes, int n_in,
                              void* d_out, int out_size, void* d_ws, size_t ws_size,
                              hipStream_t stream) {
    const float* x    = (const float*)d_in[0];
    const int*   sid  = (const int*)d_in[1];
    const float* W    = (const float*)d_in[2];
    const float* bias = (const float*)d_in[3];
    float*       out  = (float*)d_out;
    float*       part = (float*)d_ws;   // NDC*Bn*ON floats = 4.096 MB

    main_kernel<<<dim3(16, NDC, Sn), dim3(256), 0, stream>>>(x, sid, W, part);
    reduce_kernel<<<dim3(Bn), dim3(256), 0, stream>>>(sid, bias, part, out);
}

// Round 5
// 108.723 us; speedup vs baseline: 1.2947x; 1.0443x over previous
//
#include <hip/hip_runtime.h>
#include <stdint.h>

// Problem constants (match reference)
#define Bn   256
#define Dn   2048
#define Sn   8
#define ON   1000

// Tiling
#define ROWS 64             // max samples per subject (binomial mean 32; 6+ sigma)
#define OT   256            // o per block (4 oc blocks; oc=3 ragged, clamped)
#define KS   256            // k per block
#define NDC  (Dn / KS)      // 8 part slices
#define STK  32             // k per sub-tile
#define NST  (KS / STK)     // 8 sub-tiles, double-buffered
#define LDKS 40             // shorts per o-row in Bsh: 32 k + 8 pad = 80B (16B multiple)
#define BUFB (OT * LDKS * 2) // bytes per LDS buffer = 20480

typedef short v8s __attribute__((ext_vector_type(8)));
typedef short v4s __attribute__((ext_vector_type(4)));
typedef float v4f __attribute__((ext_vector_type(4)));

// fp32 -> bf16 round-to-nearest-even
static __device__ __forceinline__ short f2bf(float f) {
    union { float f; uint32_t u; } v; v.f = f;
    uint32_t u = v.u;
    u += 0x7FFFu + ((u >> 16) & 1u);
    return (short)(u >> 16);
}

// Pre-pass (round-1 proven): bucket-gather x rows by subject, convert to bf16.
// xg[s][r][d], rows padded to ROWS with zeros. Grid (ROWS, Sn), 256 thr.
__global__ __launch_bounds__(256) void gather_kernel(const float* __restrict__ x,
                                                     const int* __restrict__ sid,
                                                     unsigned short* __restrict__ xg) {
    __shared__ unsigned long long bmask[4];
    __shared__ int brow;
    const int r = blockIdx.x;
    const int s = blockIdx.y;
    const int t = threadIdx.x;
    const int lane = t & 63;
    const int wave = t >> 6;

    const bool match = (sid[t] == s);
    const unsigned long long m = __ballot(match);
    if (lane == 0) bmask[wave] = m;
    if (t == 0) brow = -1;
    __syncthreads();
    if (match) {
        int pos = __popcll(m & ((1ull << lane) - 1ull));
        for (int w = 0; w < wave; ++w) pos += __popcll(bmask[w]);
        if (pos == r) brow = t;
    }
    __syncthreads();

    const int b = brow;
    v8s v = (v8s){0, 0, 0, 0, 0, 0, 0, 0};
    if (b >= 0) {
        const float4 f0 = *(const float4*)(x + (size_t)b * Dn + t * 8);
        const float4 f1 = *(const float4*)(x + (size_t)b * Dn + t * 8 + 4);
        v[0] = f2bf(f0.x); v[1] = f2bf(f0.y); v[2] = f2bf(f0.z); v[3] = f2bf(f0.w);
        v[4] = f2bf(f1.x); v[5] = f2bf(f1.y); v[6] = f2bf(f1.z); v[7] = f2bf(f1.w);
    }
    *(v8s*)(xg + ((size_t)s * ROWS + r) * Dn + t * 8) = v;
}

// Main kernel: grid (4 oc, 8 kc, 8 s) = 256 blocks, 512 threads (8 waves).
// DRAM-locality design: every wave-load = 64 lanes x float4 = 1KB CONTIGUOUS
// along o (one full 256-o row-slice per instruction) — vs the 256B strided
// requests of rounds 0-3 that pinned the stream at ~1.3 TB/s.
// The o-major loads are transposed in registers (4o x 4k per thread) into the
// [o][k]-major bf16 LDS tile via 4x ds_write_b64, granule-XOR swizzled so
// b128 frag reads are ~2-way (free). Sub-tiles (32k) double-buffered with one
// raw s_barrier + lgkmcnt(0) each; vmcnt is never drained — next sub-tile's
// loads stay in flight across the barrier.
__global__ __launch_bounds__(512) void main_kernel(const unsigned short* __restrict__ xg,
                                                   const int* __restrict__ sid,
                                                   const float* __restrict__ W,
                                                   float* __restrict__ part) {
    __shared__ unsigned short Bsh[2][OT * LDKS];   // 2 x 20KB
    __shared__ unsigned long long bmask[8];
    __shared__ int rows_l[ROWS];

    const int oc = blockIdx.x;   // 0..3
    const int kc = blockIdx.y;   // 0..7
    const int s  = blockIdx.z;   // 0..7
    const int o0 = oc * OT;
    const int k0 = kc * KS;
    const int t  = threadIdx.x;
    const int lane = t & 63;
    const int w    = t >> 6;     // 0..7

    // ---- bucket samples of subject s via ballot (prefix-dense rows_l) ----
    const int mysid = (t < Bn) ? sid[t] : -1;
    const bool match = (mysid == s);
    const unsigned long long m = __ballot(match);
    if (lane == 0) bmask[w] = m;
    if (t < ROWS) rows_l[t] = -1;
    __syncthreads();
    if (match) {
        int pos = __popcll(m & ((1ull << lane) - 1ull));
        for (int ww = 0; ww < w; ++ww) pos += __popcll(bmask[ww]);
        if (pos < ROWS) rows_l[pos] = t;
    }
    __syncthreads();

    // ---- W staging geometry: wave w covers k-rows 4w..4w+3 of each sub-tile;
    //      lane covers o = o0 + 4*lane .. +3 (contiguous 1KB per wave-instr) ----
    int og = o0 + 4 * lane;
    if (og > ON - 4) og = ON - 4;               // oc=3 ragged: duplicate loads, local col kept
    const float* wpb = W + ((size_t)s * Dn + k0 + 4 * w) * ON + og;

    // LDS write addrs (buffer 0): b64 of k=4w..4w+3 at o=4*lane+i.
    // byte = o*80 + 16*((w>>1) ^ (lane&3)) + 8*(w&1)   [granule-XOR swizzle]
    unsigned short* wr[4];
#pragma unroll
    for (int i = 0; i < 4; ++i)
        wr[i] = (unsigned short*)((char*)&Bsh[0][0]
                + (4 * lane + i) * 80 + 16 * ((w >> 1) ^ (lane & 3)) + 8 * (w & 1));

    // ---- A geometry: wave w -> rows (w>>1)*16..+15, o-half (w&1) ----
    const int lo16 = lane & 15;
    const int quad = lane >> 4;
    const int arow = (w >> 1) * 16 + lo16;
    const bool wactive = (rows_l[(w >> 1) * 16] >= 0);    // prefix-dense
    const unsigned short* xr = xg + ((size_t)s * ROWS + arow) * Dn + k0 + quad * 8;

    // prefetch all 8 A-fragments (L2-resident xg, issued FIRST so their vmcnt
    // waits never force the W stream to drain)
    v8s af[NST];
#pragma unroll
    for (int st = 0; st < NST; ++st) af[st] = *(const v8s*)(xr + st * STK);

    // B-frag read base: o_loc = (w&1)*128 + nt*16 + lo16; granule swizzle by lo16
    const int rb0  = (w & 1) * 128 + lo16;
    const int rswz = 16 * (quad ^ ((lo16 >> 2) & 3));

    // ---- prologue: issue sub-tiles 0,1 (4 x float4 each = 32 VGPRs total) ----
    v4f fb[2][4];
#pragma unroll
    for (int c = 0; c < 2; ++c)
#pragma unroll
        for (int r = 0; r < 4; ++r)
            fb[c][r] = *(const v4f*)(wpb + ((size_t)c * STK + r) * ON);

    v4f acc[8];
#pragma unroll
    for (int i = 0; i < 8; ++i) acc[i] = (v4f){0.f, 0.f, 0.f, 0.f};

    // ---- main loop: one barrier per 32-k sub-tile, counted vmcnt throughout ----
#pragma unroll
    for (int st = 0; st < NST; ++st) {
        const int sl = st & 1;
        // register transpose: 4o x 4k -> four b64 k-runs
#pragma unroll
        for (int i = 0; i < 4; ++i) {
            v4s kv;
            kv[0] = f2bf(fb[sl][0][i]);
            kv[1] = f2bf(fb[sl][1][i]);
            kv[2] = f2bf(fb[sl][2][i]);
            kv[3] = f2bf(fb[sl][3][i]);
            *(v4s*)((char*)wr[i] + sl * BUFB) = kv;
        }
        // issue sub-tile st+2's loads (stay in flight across the barrier)
        if (st + 2 < NST) {
#pragma unroll
            for (int r = 0; r < 4; ++r)
                fb[sl][r] = *(const v4f*)(wpb + ((size_t)(st + 2) * STK + r) * ON);
        }
        asm volatile("s_waitcnt lgkmcnt(0)" ::: "memory");
        __builtin_amdgcn_s_barrier();
        asm volatile("" ::: "memory");

        // compute sub-tile st: 8 MFMA per wave (rows x 128-o-half x 32k)
        if (wactive) {
            const v8s a = af[st];
            const char* bb = (const char*)&Bsh[sl][0];
#pragma unroll
            for (int nt = 0; nt < 8; ++nt) {
                const v8s bf = *(const v8s*)(bb + (rb0 + nt * 16) * 80 + rswz);
                acc[nt] = __builtin_amdgcn_mfma_f32_16x16x32_bf16(a, bf, acc[nt],
                                                                  0, 0, 0);
            }
        }
    }

    // ---- epilogue: C/D layout col=lane&15, row=quad*4+reg ----
    if (wactive) {
        float* pp = part + (size_t)kc * Bn * ON;
        const int er0 = (w >> 1) * 16 + quad * 4;
#pragma unroll
        for (int nt = 0; nt < 8; ++nt) {
            const int o = o0 + (w & 1) * 128 + nt * 16 + lo16;
            if (o < ON) {
#pragma unroll
                for (int r = 0; r < 4; ++r) {
                    const int bi = rows_l[er0 + r];
                    if (bi >= 0) pp[(size_t)bi * ON + o] = acc[nt][r];
                }
            }
        }
    }
}

// Reduce: out[b][o] = bias[sid[b]][o] + sum_kc part[kc][b][o]  (float4 lanes)
__global__ __launch_bounds__(256) void reduce_kernel(const int* __restrict__ sid,
                                                     const float* __restrict__ bias,
                                                     const float* __restrict__ part,
                                                     float* __restrict__ out) {
    const int b = blockIdx.x;
    const int s = sid[b];
    const int o = threadIdx.x * 4;
    if (o < ON) {          // ON=1000 -> 250 active float4 lanes
        float4 v = *(const float4*)(bias + (size_t)s * ON + o);
#pragma unroll
        for (int d = 0; d < NDC; d++) {
            const float4 p = *(const float4*)(part + ((size_t)d * Bn + b) * ON + o);
            v.x += p.x; v.y += p.y; v.z += p.z; v.w += p.w;
        }
        *(float4*)(out + (size_t)b * ON + o) = v;
    }
}

extern "C" void kernel_launch(void* const* d_in, const int* in_sizes, int n_in,
                              void* d_out, int out_size, void* d_ws, size_t ws_size,
                              hipStream_t stream) {
    const float* x    = (const float*)d_in[0];
    const int*   sid  = (const int*)d_in[1];
    const float* W    = (const float*)d_in[2];
    const float* bias = (const float*)d_in[3];
    float*       out  = (float*)d_out;
    float*       part = (float*)d_ws;   // NDC*Bn*ON floats = 8.192 MB
    unsigned short* xg = (unsigned short*)((char*)d_ws + (size_t)NDC * Bn * ON * sizeof(float));
                                         // 8*64*2048 bf16 = 2.1 MB, 16B-aligned

    gather_kernel<<<dim3(ROWS, Sn), dim3(256), 0, stream>>>(x, sid, xg);
    main_kernel<<<dim3(4, NDC, Sn), dim3(512), 0, stream>>>(xg, sid, W, part);
    reduce_kernel<<<dim3(Bn), dim3(256), 0, stream>>>(sid, bias, part, out);
}

// Round 6
// 106.753 us; speedup vs baseline: 1.3186x; 1.0185x over previous
//
#include <hip/hip_runtime.h>
#include <stdint.h>

// Problem constants (match reference)
#define Bn   256
#define Dn   2048
#define Sn   8
#define ON   1000

// Tiling
#define ROWS 64             // max samples per subject (binomial mean 32; 6+ sigma)
#define OT   256            // o per block (4 oc blocks; oc=3 ragged, clamped)
#define KS   256            // k per block
#define NDC  (Dn / KS)      // 8 part slices
#define STK  32             // k per sub-tile
#define NST  (KS / STK)     // 8 sub-tiles, double-buffered LDS, depth-3 W ring
#define LDKS 40             // shorts per o-row in Bsh: 32 k + 8 pad = 80B (16B multiple)
#define BUFB (OT * LDKS * 2) // bytes per LDS buffer = 20480

typedef short v8s __attribute__((ext_vector_type(8)));
typedef short v4s __attribute__((ext_vector_type(4)));
typedef float v4f __attribute__((ext_vector_type(4)));

// fp32 -> bf16 round-to-nearest-even
static __device__ __forceinline__ short f2bf(float f) {
    union { float f; uint32_t u; } v; v.f = f;
    uint32_t u = v.u;
    u += 0x7FFFu + ((u >> 16) & 1u);
    return (short)(u >> 16);
}

// Main kernel: grid (4 oc, 8 kc, 8 s) = 256 blocks, 512 threads (8 waves).
// R5-proven DRAM-locality core: every W wave-load = 64 lanes x float4 = 1KB
// CONTIGUOUS along o; register 4o x 4k transpose -> granule-XOR-swizzled
// [o][k] bf16 LDS tile; one raw s_barrier + lgkmcnt(0) per 32-k sub-tile,
// vmcnt never drained.
// New vs R5: (1) gather_kernel removed — A-fragments convert inline from x
// (issued FIRST so their vmcnt retire before the W stream's); (2) W prefetch
// ring deepened 2 -> 3 sub-tiles (static indices via full unroll).
__global__ __launch_bounds__(512) void main_kernel(const float* __restrict__ x,
                                                   const int* __restrict__ sid,
                                                   const float* __restrict__ W,
                                                   float* __restrict__ part) {
    __shared__ unsigned short Bsh[2][OT * LDKS];   // 2 x 20KB
    __shared__ unsigned long long bmask[8];
    __shared__ int rows_l[ROWS];

    const int oc = blockIdx.x;   // 0..3
    const int kc = blockIdx.y;   // 0..7
    const int s  = blockIdx.z;   // 0..7
    const int o0 = oc * OT;
    const int k0 = kc * KS;
    const int t  = threadIdx.x;
    const int lane = t & 63;
    const int w    = t >> 6;     // 0..7

    // ---- bucket samples of subject s via ballot (prefix-dense rows_l) ----
    const int mysid = (t < Bn) ? sid[t] : -1;
    const bool match = (mysid == s);
    const unsigned long long m = __ballot(match);
    if (lane == 0) bmask[w] = m;
    if (t < ROWS) rows_l[t] = -1;
    __syncthreads();
    if (match) {
        int pos = __popcll(m & ((1ull << lane) - 1ull));
        for (int ww = 0; ww < w; ++ww) pos += __popcll(bmask[ww]);
        if (pos < ROWS) rows_l[pos] = t;
    }
    __syncthreads();

    // ---- W staging geometry: wave w covers k-rows 4w..4w+3 of each sub-tile;
    //      lane covers o = o0 + 4*lane .. +3 (contiguous 1KB per wave-instr) ----
    int og = o0 + 4 * lane;
    if (og > ON - 4) og = ON - 4;               // oc=3 ragged: duplicate loads, local col kept
    const float* wpb = W + ((size_t)s * Dn + k0 + 4 * w) * ON + og;

    // LDS write addrs (buffer 0): b64 of k=4w..4w+3 at o=4*lane+i.
    // byte = o*80 + 16*((w>>1) ^ (lane&3)) + 8*(w&1)   [granule-XOR swizzle]
    unsigned short* wr[4];
#pragma unroll
    for (int i = 0; i < 4; ++i)
        wr[i] = (unsigned short*)((char*)&Bsh[0][0]
                + (4 * lane + i) * 80 + 16 * ((w >> 1) ^ (lane & 3)) + 8 * (w & 1));

    // ---- A geometry: wave w -> rows (w>>1)*16..+15, o-half (w&1) ----
    const int lo16 = lane & 15;
    const int quad = lane >> 4;
    const int arow = (w >> 1) * 16 + lo16;
    const int xrow = rows_l[arow];
    const bool wactive = (rows_l[(w >> 1) * 16] >= 0);    // prefix-dense
    const float* xp = (xrow >= 0 ? x + (size_t)xrow * Dn : x) + k0 + quad * 8;

    // ---- A loads issued FIRST (L2/L3-resident x, oldest in vmcnt order so
    //      waiting on them never drains the younger W stream) ----
    float4 a0[NST], a1[NST];
#pragma unroll
    for (int st = 0; st < NST; ++st) {
        a0[st] = *(const float4*)(xp + st * STK);
        a1[st] = *(const float4*)(xp + st * STK + 4);
    }

    // ---- W prologue: issue sub-tiles 0,1,2 (depth-3 ring, 48 VGPRs) ----
    v4f fb[3][4];
#pragma unroll
    for (int c = 0; c < 3; ++c)
#pragma unroll
        for (int r = 0; r < 4; ++r)
            fb[c][r] = *(const v4f*)(wpb + ((size_t)c * STK + r) * ON);

    // ---- convert A to bf16 fragments (frees the 64 raw VGPRs) ----
    v8s af[NST];
#pragma unroll
    for (int st = 0; st < NST; ++st) {
        v8s a;
        a[0] = f2bf(a0[st].x); a[1] = f2bf(a0[st].y);
        a[2] = f2bf(a0[st].z); a[3] = f2bf(a0[st].w);
        a[4] = f2bf(a1[st].x); a[5] = f2bf(a1[st].y);
        a[6] = f2bf(a1[st].z); a[7] = f2bf(a1[st].w);
        af[st] = a;
    }

    // B-frag read base: o_loc = (w&1)*128 + nt*16 + lo16; granule swizzle by lo16
    const int rb0  = (w & 1) * 128 + lo16;
    const int rswz = 16 * (quad ^ ((lo16 >> 2) & 3));

    v4f acc[8];
#pragma unroll
    for (int i = 0; i < 8; ++i) acc[i] = (v4f){0.f, 0.f, 0.f, 0.f};

    // ---- main loop: one barrier per 32-k sub-tile, counted vmcnt throughout.
    //      Fully unrolled -> fb[st%3] indices are compile-time constants. ----
#pragma unroll
    for (int st = 0; st < NST; ++st) {
        const int sl = st & 1;          // LDS buffer
        const int rg = st % 3;          // W ring slot
        // register transpose: 4o x 4k -> four b64 k-runs
#pragma unroll
        for (int i = 0; i < 4; ++i) {
            v4s kv;
            kv[0] = f2bf(fb[rg][0][i]);
            kv[1] = f2bf(fb[rg][1][i]);
            kv[2] = f2bf(fb[rg][2][i]);
            kv[3] = f2bf(fb[rg][3][i]);
            *(v4s*)((char*)wr[i] + sl * BUFB) = kv;
        }
        // issue sub-tile st+3's loads (stay in flight across the barrier)
        if (st + 3 < NST) {
#pragma unroll
            for (int r = 0; r < 4; ++r)
                fb[rg][r] = *(const v4f*)(wpb + ((size_t)(st + 3) * STK + r) * ON);
        }
        asm volatile("s_waitcnt lgkmcnt(0)" ::: "memory");
        __builtin_amdgcn_s_barrier();
        asm volatile("" ::: "memory");

        // compute sub-tile st: 8 MFMA per wave (16 rows x 128-o-half x 32k)
        if (wactive) {
            const v8s a = af[st];
            const char* bb = (const char*)&Bsh[sl][0];
#pragma unroll
            for (int nt = 0; nt < 8; ++nt) {
                const v8s bf = *(const v8s*)(bb + (rb0 + nt * 16) * 80 + rswz);
                acc[nt] = __builtin_amdgcn_mfma_f32_16x16x32_bf16(a, bf, acc[nt],
                                                                  0, 0, 0);
            }
        }
    }

    // ---- epilogue: C/D layout col=lane&15, row=quad*4+reg ----
    if (wactive) {
        float* pp = part + (size_t)kc * Bn * ON;
        const int er0 = (w >> 1) * 16 + quad * 4;
#pragma unroll
        for (int nt = 0; nt < 8; ++nt) {
            const int o = o0 + (w & 1) * 128 + nt * 16 + lo16;
            if (o < ON) {
#pragma unroll
                for (int r = 0; r < 4; ++r) {
                    const int bi = rows_l[er0 + r];
                    if (bi >= 0) pp[(size_t)bi * ON + o] = acc[nt][r];
                }
            }
        }
    }
}

// Reduce: out[b][o] = bias[sid[b]][o] + sum_kc part[kc][b][o]  (float4 lanes)
__global__ __launch_bounds__(256) void reduce_kernel(const int* __restrict__ sid,
                                                     const float* __restrict__ bias,
                                                     const float* __restrict__ part,
                                                     float* __restrict__ out) {
    const int b = blockIdx.x;
    const int s = sid[b];
    const int o = threadIdx.x * 4;
    if (o < ON) {          // ON=1000 -> 250 active float4 lanes
        float4 v = *(const float4*)(bias + (size_t)s * ON + o);
#pragma unroll
        for (int d = 0; d < NDC; d++) {
            const float4 p = *(const float4*)(part + ((size_t)d * Bn + b) * ON + o);
            v.x += p.x; v.y += p.y; v.z += p.z; v.w += p.w;
        }
        *(float4*)(out + (size_t)b * ON + o) = v;
    }
}

extern "C" void kernel_launch(void* const* d_in, const int* in_sizes, int n_in,
                              void* d_out, int out_size, void* d_ws, size_t ws_size,
                              hipStream_t stream) {
    const float* x    = (const float*)d_in[0];
    const int*   sid  = (const int*)d_in[1];
    const float* W    = (const float*)d_in[2];
    const float* bias = (const float*)d_in[3];
    float*       out  = (float*)d_out;
    float*       part = (float*)d_ws;   // NDC*Bn*ON floats = 8.192 MB

    main_kernel<<<dim3(4, NDC, Sn), dim3(512), 0, stream>>>(x, sid, W, part);
    reduce_kernel<<<dim3(Bn), dim3(256), 0, stream>>>(sid, bias, part, out);
}